// Round 5
// baseline (422.686 us; speedup 1.0000x reference)
//
#include <hip/hip_runtime.h>

// Problem constants
#define Hn  16
#define Dh  64
#define Bb  4
#define Tn  2048
#define En  1024
#define Mn  8192           // B*T
#define N1  3072           // 3*E
#define Kn  1024           // E
#define BHT (Bb*Hn*Tn)     // 262144

typedef __attribute__((ext_vector_type(8)))  short  short8;
typedef __attribute__((ext_vector_type(4)))  short  short4v;
typedef __attribute__((ext_vector_type(4)))  float  f32x4;
typedef __attribute__((ext_vector_type(8)))  __bf16 bf16x8;

__device__ __forceinline__ float b2f(short s) {
  unsigned u = ((unsigned)(unsigned short)s) << 16;
  return __builtin_bit_cast(float, u);
}
__device__ __forceinline__ short f2b(float f) {
  unsigned u = __builtin_bit_cast(unsigned, f);
  u += 0x7fffu + ((u >> 16) & 1u);
  return (short)(u >> 16);
}
__device__ __forceinline__ f32x4 mfma16(short8 a, short8 b, f32x4 c) {
  return __builtin_amdgcn_mfma_f32_16x16x32_bf16(
      __builtin_bit_cast(bf16x8, a), __builtin_bit_cast(bf16x8, b), c, 0, 0, 0);
}
__device__ __forceinline__ void gload16(const void* g, void* l) {
  __builtin_amdgcn_global_load_lds(
      (const __attribute__((address_space(1))) unsigned int*)g,
      (__attribute__((address_space(3))) unsigned int*)l, 16, 0, 0);
}

// ---------------- cast x -> bf16 ----------------
__global__ __launch_bounds__(256) void cvt_x_kernel(const float* __restrict__ x,
                                                    short* __restrict__ xb) {
  const size_t i = ((size_t)blockIdx.x * 256 + threadIdx.x) * 8;
  f32x4 a = *(const f32x4*)&x[i];
  f32x4 b = *(const f32x4*)&x[i + 4];
  short8 o;
  o[0]=f2b(a[0]); o[1]=f2b(a[1]); o[2]=f2b(a[2]); o[3]=f2b(a[3]);
  o[4]=f2b(b[0]); o[5]=f2b(b[1]); o[6]=f2b(b[2]); o[7]=f2b(b[3]);
  *(short8*)&xb[i] = o;
}

// ---------------- transpose W [R][C] f32 -> [C][R] bf16 ----------------
__global__ __launch_bounds__(256) void transpose_w_kernel(const float* __restrict__ in,
                                                          short* __restrict__ out,
                                                          int R, int C) {
  __shared__ float tile[32][33];
  const int tid = threadIdx.x;
  const int c0 = blockIdx.x * 32, r0 = blockIdx.y * 32;
  const int lr = tid >> 3, lc = (tid & 7) * 4;
  f32x4 v = *(const f32x4*)&in[(size_t)(r0 + lr) * C + c0 + lc];
  tile[lr][lc] = v[0]; tile[lr][lc+1] = v[1]; tile[lr][lc+2] = v[2]; tile[lr][lc+3] = v[3];
  __syncthreads();
  const int oc = tid >> 3, orr = (tid & 7) * 4;
  short4v ov;
  ov[0] = f2b(tile[orr][oc]);   ov[1] = f2b(tile[orr+1][oc]);
  ov[2] = f2b(tile[orr+2][oc]); ov[3] = f2b(tile[orr+3][oc]);
  *(short4v*)&out[(size_t)(c0 + oc) * R + r0 + orr] = ov;
}

// ---------------- GEMM: C[M][N] = A[M][K] * Bt[N][K]^T + bias ----------------
template<int MODE>
__global__ __launch_bounds__(256) void gemm_kernel(
    const short* __restrict__ A, const short* __restrict__ Bt,
    const float* __restrict__ bias, float* __restrict__ Cf,
    short* __restrict__ qo, short* __restrict__ ko2, short* __restrict__ vo,
    int N) {
  __shared__ short As[4096];
  __shared__ short Bs[4096];
  const int tid = threadIdx.x, lane = tid & 63, w = tid >> 6;
  const int rowBase = blockIdx.y * 128, colBase = blockIdx.x * 128;
  f32x4 acc[4][4] = {};
  const int srow = tid >> 2, sk = (tid & 3) << 3;
  const short* Ag = A  + (size_t)(rowBase + srow) * Kn + sk;
  const short* Bg = Bt + (size_t)(colBase + srow) * Kn + sk;
  short* AsW = As + w * 512;
  short* BsW = Bs + w * 512;
  const int ar = (w >> 1) * 64, bc = (w & 1) * 64;
  const int lg8 = (lane >> 4) * 8, lr = lane & 15;

  for (int kt = 0; kt < Kn; kt += 32) {
    __syncthreads();
    gload16(Ag + kt,            AsW);
    gload16(Ag + kt + 64 * Kn,  AsW + 2048);
    gload16(Bg + kt,            BsW);
    gload16(Bg + kt + 64 * Kn,  BsW + 2048);
    __syncthreads();
    short8 af[4], bfr[4];
#pragma unroll
    for (int m = 0; m < 4; ++m) af[m]  = *(const short8*)&As[(ar + m*16 + lr)*32 + lg8];
#pragma unroll
    for (int n = 0; n < 4; ++n) bfr[n] = *(const short8*)&Bs[(bc + n*16 + lr)*32 + lg8];
#pragma unroll
    for (int m = 0; m < 4; ++m)
#pragma unroll
      for (int n = 0; n < 4; ++n)
        acc[m][n] = mfma16(af[m], bfr[n], acc[m][n]);
  }

  const int gr0 = rowBase + ar + (lane >> 4) * 4;
  const int gc0 = colBase + bc + lr;
#pragma unroll
  for (int m = 0; m < 4; ++m) {
#pragma unroll
    for (int n = 0; n < 4; ++n) {
      const int gc = gc0 + n * 16;
      const float bb = bias[gc];
#pragma unroll
      for (int r = 0; r < 4; ++r) {
        const int gr = gr0 + m * 16 + r;
        const float v = acc[m][n][r] + bb;
        if (MODE == 0) {
          Cf[(size_t)gr * N + gc] = v;
        } else {
          const int which = gc >> 10, e = gc & 1023;
          const int hh = e >> 6, d = e & 63;
          const int bidx = gr >> 11, t = gr & 2047;
          const size_t idx = ((size_t)(bidx * Hn + hh) * Tn + t) * Dh + d;
          short* dst = (which == 0) ? qo : (which == 1) ? ko2 : vo;
          dst[idx] = f2b(v);
        }
      }
    }
  }
}

// ---------------- LayerNorm over D=64; q gets 1/sqrt(D)*log2(e) folded ----------------
__global__ __launch_bounds__(256) void ln_qk_kernel(short* __restrict__ qp, short* __restrict__ kp,
                                                    const float* __restrict__ qg, const float* __restrict__ qb,
                                                    const float* __restrict__ kg, const float* __restrict__ kb) {
  const int lane = threadIdx.x & 63;
  const int rp = blockIdx.x * 4 + (threadIdx.x >> 6);
  const size_t base = (size_t)rp * 64 + lane;
  float xq = b2f(qp[base]);
  float xk = b2f(kp[base]);
  float sq = xq, sk = xk;
#pragma unroll
  for (int off = 1; off < 64; off <<= 1) { sq += __shfl_xor(sq, off); sk += __shfl_xor(sk, off); }
  const float muq = sq * (1.f/64), muk = sk * (1.f/64);
  const float dq = xq - muq, dk = xk - muk;
  float vq = dq * dq, vk = dk * dk;
#pragma unroll
  for (int off = 1; off < 64; off <<= 1) { vq += __shfl_xor(vq, off); vk += __shfl_xor(vk, off); }
  const float rq = rsqrtf(vq * (1.f/64) + 1e-5f);
  const float rk = rsqrtf(vk * (1.f/64) + 1e-5f);
  // fold 1/sqrt(D)=0.125 and log2(e): attention softmax runs in exp2 domain
  const float yq = (dq * rq * qg[lane] + qb[lane]) * (0.125f * 1.44269504088896f);
  const float yk =  dk * rk * kg[lane] + kb[lane];
  qp[base] = f2b(yq);
  kp[base] = f2b(yk);
}

// ---------------- V [bh][t][d] -> Vt [bh][d][t] ----------------
__global__ __launch_bounds__(256) void transpose_v_kernel(const short* __restrict__ vp,
                                                          short* __restrict__ vt) {
  __shared__ short tile[64][72];
  const int tid = threadIdx.x;
  const int bh = blockIdx.y, jt = blockIdx.x;
  const short* src = vp + ((size_t)bh * Tn + jt * 64) * Dh;
#pragma unroll
  for (int i = 0; i < 4; ++i) {
    const int idx = i * 1024 + tid * 4;
    short4v v = *(const short4v*)&src[idx];
    const int r = idx >> 6, c = idx & 63;
    tile[r][c] = v[0]; tile[r][c+1] = v[1]; tile[r][c+2] = v[2]; tile[r][c+3] = v[3];
  }
  __syncthreads();
  short* dst = vt + (size_t)bh * Dh * Tn + jt * 64;
#pragma unroll
  for (int i = 0; i < 4; ++i) {
    const int idx = i * 1024 + tid * 4;
    const int d = idx >> 6, t0 = idx & 63;
    short4v v;
    v[0] = tile[t0][d]; v[1] = tile[t0+1][d]; v[2] = tile[t0+2][d]; v[3] = tile[t0+3][d];
    *(short4v*)&dst[(size_t)d * Tn + t0] = v;
  }
}

// ---------------- Flash attention (proven 16x16 structure, 8-wave blocks) ----------------
// 512 blocks (XCD-swizzled -> (bh,qt)), 8 waves x 32 q-rows = 256 q-rows/block.
// 2 blocks/CU resident (64KB LDS, 112 VGPR) -> 4 waves/SIMD, zero grid tail.
// Softmax path byte-identical to round 4 (exp2 domain, defer-max, deferred
// row-sum, truncating P-store with bias-cancelling lpart).
__global__ __launch_bounds__(512, 4) void flash_kernel(
    const short* __restrict__ qp, const short* __restrict__ kp,
    const short* __restrict__ vt, short* __restrict__ y) {
  __shared__ short Ks[2][4096];   // [buf][64 keys][64 d] (swizzled)
  __shared__ short Vs[2][4096];   // [buf][64 d][64 keys] (swizzled)
  __shared__ short Ps[16384];     // per-wave 2048 shorts: [32 q][64 k]
  const int tid = threadIdx.x, lane = tid & 63, w = tid >> 6;   // w = 0..7
  const int lr = lane & 15, lg = lane >> 4;

  // XCD swizzle (bijective over 512 = 8 XCD x 8 bh x 8 qt)
  const int j0 = blockIdx.x;
  const int xcd = j0 & 7, idx = j0 >> 3;
  const int bh = 8 * xcd + (idx & 7), qt = idx >> 3;

  const int qrow0 = qt * 256 + w * 32;
  const short* qbase = qp + ((size_t)bh * Tn + qrow0) * Dh;

  short8 aq[2][2];
#pragma unroll
  for (int m = 0; m < 2; ++m)
#pragma unroll
    for (int kk = 0; kk < 2; ++kk)
      aq[m][kk] = *(const short8*)&qbase[(m*16 + lr)*64 + kk*32 + lg*8];

  f32x4 o[2][4] = {};
  float mrow[2][4], lpart[2][4];
#pragma unroll
  for (int m = 0; m < 2; ++m)
#pragma unroll
    for (int r = 0; r < 4; ++r) { mrow[m][r] = -3e38f; lpart[m][r] = 0.f; }

  const int srow = tid >> 3;         // 0..63
  const int sc = (tid & 7) * 8;      // shorts
  const int scs = sc ^ ((srow & 7) << 3);   // pre-swizzled source column
  short* Pw = Ps + w * 2048;
  const short* kb = kp + (size_t)bh * Tn * Dh + scs;
  const short* vb = vt + (size_t)bh * Dh * Tn + (size_t)srow * Tn + scs;

  // one K-load + one V-load per thread per tile (512 threads x 16B = 8KB tile)
#define STAGE(jt, bsel)                                                   \
  {                                                                       \
    gload16(kb + (size_t)((jt) * 64 + srow) * Dh, &Ks[bsel][tid * 8]);    \
    gload16(vb + (jt) * 64,                       &Vs[bsel][tid * 8]);    \
  }

  STAGE(0, 0);
  __syncthreads();

  for (int j = 0; j < Tn / 64; ++j) {
    const int cur = j & 1;
    if (j + 1 < Tn / 64) STAGE(j + 1, cur ^ 1);

    // S = Q K^T  (C: row=q=lg*4+r+16m, col=key=lr+16n)
    short8 bk[4][2];
#pragma unroll
    for (int n = 0; n < 4; ++n)
#pragma unroll
      for (int kk = 0; kk < 2; ++kk) {
        const int row = n * 16 + lr;
        bk[n][kk] = *(const short8*)&Ks[cur][row*64 + ((kk*32 + lg*8) ^ ((row & 7) << 3))];
      }
    f32x4 s[2][4] = {};
    __builtin_amdgcn_s_setprio(1);
#pragma unroll
    for (int m = 0; m < 2; ++m)
#pragma unroll
      for (int n = 0; n < 4; ++n) {
        s[m][n] = mfma16(aq[m][0], bk[n][0], s[m][n]);
        s[m][n] = mfma16(aq[m][1], bk[n][1], s[m][n]);
      }
    __builtin_amdgcn_s_setprio(0);

    // defer-max: per-lane partial max vs stale row max
    float pm[2][4];
#pragma unroll
    for (int m = 0; m < 2; ++m)
#pragma unroll
      for (int r = 0; r < 4; ++r)
        pm[m][r] = fmaxf(fmaxf(s[m][0][r], s[m][1][r]), fmaxf(s[m][2][r], s[m][3][r]));
    int ok = 1;
#pragma unroll
    for (int m = 0; m < 2; ++m)
#pragma unroll
      for (int r = 0; r < 4; ++r)
        ok &= (pm[m][r] <= mrow[m][r] + 11.0f) ? 1 : 0;
    if (!__all(ok)) {
      float tm[2][4];
#pragma unroll
      for (int m = 0; m < 2; ++m)
#pragma unroll
        for (int r = 0; r < 4; ++r) tm[m][r] = pm[m][r];
#pragma unroll
      for (int off = 1; off < 16; off <<= 1)
#pragma unroll
        for (int m = 0; m < 2; ++m)
#pragma unroll
          for (int r = 0; r < 4; ++r)
            tm[m][r] = fmaxf(tm[m][r], __shfl_xor(tm[m][r], off));
#pragma unroll
      for (int m = 0; m < 2; ++m)
#pragma unroll
        for (int r = 0; r < 4; ++r) {
          const float mn = fmaxf(mrow[m][r], tm[m][r]);
          const float corr = __builtin_amdgcn_exp2f(mrow[m][r] - mn);
          lpart[m][r] *= corr;
#pragma unroll
          for (int dn = 0; dn < 4; ++dn) o[m][dn][r] *= corr;
          mrow[m][r] = mn;
        }
    }

    // exp2, accumulate truncated partials, write P (truncated bf16)
#pragma unroll
    for (int m = 0; m < 2; ++m)
#pragma unroll
      for (int n = 0; n < 4; ++n)
#pragma unroll
        for (int r = 0; r < 4; ++r) {
          const float p = __builtin_amdgcn_exp2f(s[m][n][r] - mrow[m][r]);
          const unsigned u = __builtin_bit_cast(unsigned, p);
          lpart[m][r] += __builtin_bit_cast(float, u & 0xffff0000u);
          const int q = m*16 + lg*4 + r;
          const int k = n*16 + lr;
          Pw[q*64 + (k ^ ((q & 7) << 3))] = (short)(u >> 16);
        }

    // O += P V
    short8 pa[2][2], bv[4][2];
#pragma unroll
    for (int m = 0; m < 2; ++m)
#pragma unroll
      for (int kk = 0; kk < 2; ++kk) {
        const int q = m*16 + lr;
        pa[m][kk] = *(const short8*)&Pw[q*64 + ((kk*32 + lg*8) ^ ((q & 7) << 3))];
      }
#pragma unroll
    for (int dn = 0; dn < 4; ++dn)
#pragma unroll
      for (int kk = 0; kk < 2; ++kk) {
        const int row = dn * 16 + lr;
        bv[dn][kk] = *(const short8*)&Vs[cur][row*64 + ((kk*32 + lg*8) ^ ((row & 7) << 3))];
      }
    __builtin_amdgcn_s_setprio(1);
#pragma unroll
    for (int m = 0; m < 2; ++m)
#pragma unroll
      for (int dn = 0; dn < 4; ++dn) {
        o[m][dn] = mfma16(pa[m][0], bv[dn][0], o[m][dn]);
        o[m][dn] = mfma16(pa[m][1], bv[dn][1], o[m][dn]);
      }
    __builtin_amdgcn_s_setprio(0);

    __syncthreads();
  }
#undef STAGE

  // one row-sum tree for the whole kernel
#pragma unroll
  for (int off = 1; off < 16; off <<= 1)
#pragma unroll
    for (int m = 0; m < 2; ++m)
#pragma unroll
      for (int r = 0; r < 4; ++r)
        lpart[m][r] += __shfl_xor(lpart[m][r], off);

  // normalize + store y[B][T][E] bf16
  const int b = bh >> 4, hh = bh & 15;
  short* yb = y + (size_t)b * Tn * En + hh * 64;
#pragma unroll
  for (int m = 0; m < 2; ++m)
#pragma unroll
    for (int r = 0; r < 4; ++r) {
      const float rl = 1.0f / lpart[m][r];
      const int t = qrow0 + m*16 + lg*4 + r;
#pragma unroll
      for (int dn = 0; dn < 4; ++dn) {
        const int d = dn*16 + lr;
        yb[(size_t)t * En + d] = f2b(o[m][dn][r] * rl);
      }
    }
}

extern "C" void kernel_launch(void* const* d_in, const int* in_sizes, int n_in,
                              void* d_out, int out_size, void* d_ws, size_t ws_size,
                              hipStream_t stream) {
  const float* x     = (const float*)d_in[0];
  const float* Wqkv  = (const float*)d_in[1];
  const float* bqkv  = (const float*)d_in[2];
  const float* qg    = (const float*)d_in[3];
  const float* qb    = (const float*)d_in[4];
  const float* kg    = (const float*)d_in[5];
  const float* kb    = (const float*)d_in[6];
  const float* Wproj = (const float*)d_in[7];
  const float* bproj = (const float*)d_in[8];
  float* out = (float*)d_out;

  char* p = (char*)d_ws;
  short* xb     = (short*)p; p += (size_t)Mn * Kn * 2;
  short* wqkvT  = (short*)p; p += (size_t)N1 * Kn * 2;
  short* wprojT = (short*)p; p += (size_t)En * Kn * 2;
  short* qp     = (short*)p; p += (size_t)Mn * Kn * 2;
  short* kp     = (short*)p; p += (size_t)Mn * Kn * 2;
  short* vp     = (short*)p; p += (size_t)Mn * Kn * 2;
  short* vtb    = (short*)p; p += (size_t)Mn * Kn * 2;
  short* yb     = (short*)p; p += (size_t)Mn * Kn * 2;

  cvt_x_kernel<<<Mn * Kn / (256 * 8), 256, 0, stream>>>(x, xb);
  transpose_w_kernel<<<dim3(N1 / 32, Kn / 32), 256, 0, stream>>>(Wqkv, wqkvT, Kn, N1);
  transpose_w_kernel<<<dim3(En / 32, Kn / 32), 256, 0, stream>>>(Wproj, wprojT, Kn, En);
  gemm_kernel<1><<<dim3(N1 / 128, Mn / 128), 256, 0, stream>>>(
      xb, wqkvT, bqkv, nullptr, qp, kp, vp, N1);
  ln_qk_kernel<<<BHT / 4, 256, 0, stream>>>(qp, kp, qg, qb, kg, kb);
  transpose_v_kernel<<<dim3(Tn / 64, Bb * Hn), 256, 0, stream>>>(vp, vtb);
  flash_kernel<<<512, 512, 0, stream>>>(qp, kp, vtb, yb);
  gemm_kernel<0><<<dim3(En / 128, Mn / 128), 256, 0, stream>>>(
      yb, wprojT, bproj, out, nullptr, nullptr, nullptr, En);
}

// Round 6
// 289.890 us; speedup vs baseline: 1.4581x; 1.4581x over previous
//
#include <hip/hip_runtime.h>

// Problem constants
#define Hn  16
#define Dh  64
#define Bb  4
#define Tn  2048
#define En  1024
#define Mn  8192           // B*T
#define N1  3072           // 3*E
#define Kn  1024           // E
#define BHT (Bb*Hn*Tn)     // 262144

typedef __attribute__((ext_vector_type(8)))  short  short8;
typedef __attribute__((ext_vector_type(4)))  short  short4v;
typedef __attribute__((ext_vector_type(4)))  float  f32x4;
typedef __attribute__((ext_vector_type(8)))  __bf16 bf16x8;

__device__ __forceinline__ float b2f(short s) {
  unsigned u = ((unsigned)(unsigned short)s) << 16;
  return __builtin_bit_cast(float, u);
}
__device__ __forceinline__ short f2b(float f) {
  unsigned u = __builtin_bit_cast(unsigned, f);
  u += 0x7fffu + ((u >> 16) & 1u);
  return (short)(u >> 16);
}
__device__ __forceinline__ f32x4 mfma16(short8 a, short8 b, f32x4 c) {
  return __builtin_amdgcn_mfma_f32_16x16x32_bf16(
      __builtin_bit_cast(bf16x8, a), __builtin_bit_cast(bf16x8, b), c, 0, 0, 0);
}
__device__ __forceinline__ void gload16(const void* g, void* l) {
  __builtin_amdgcn_global_load_lds(
      (const __attribute__((address_space(1))) unsigned int*)g,
      (__attribute__((address_space(3))) unsigned int*)l, 16, 0, 0);
}

// ---------------- cast x -> bf16 ----------------
__global__ __launch_bounds__(256) void cvt_x_kernel(const float* __restrict__ x,
                                                    short* __restrict__ xb) {
  const size_t i = ((size_t)blockIdx.x * 256 + threadIdx.x) * 8;
  f32x4 a = *(const f32x4*)&x[i];
  f32x4 b = *(const f32x4*)&x[i + 4];
  short8 o;
  o[0]=f2b(a[0]); o[1]=f2b(a[1]); o[2]=f2b(a[2]); o[3]=f2b(a[3]);
  o[4]=f2b(b[0]); o[5]=f2b(b[1]); o[6]=f2b(b[2]); o[7]=f2b(b[3]);
  *(short8*)&xb[i] = o;
}

// ---------------- transpose W [R][C] f32 -> [C][R] bf16 ----------------
__global__ __launch_bounds__(256) void transpose_w_kernel(const float* __restrict__ in,
                                                          short* __restrict__ out,
                                                          int R, int C) {
  __shared__ float tile[32][33];
  const int tid = threadIdx.x;
  const int c0 = blockIdx.x * 32, r0 = blockIdx.y * 32;
  const int lr = tid >> 3, lc = (tid & 7) * 4;
  f32x4 v = *(const f32x4*)&in[(size_t)(r0 + lr) * C + c0 + lc];
  tile[lr][lc] = v[0]; tile[lr][lc+1] = v[1]; tile[lr][lc+2] = v[2]; tile[lr][lc+3] = v[3];
  __syncthreads();
  const int oc = tid >> 3, orr = (tid & 7) * 4;
  short4v ov;
  ov[0] = f2b(tile[orr][oc]);   ov[1] = f2b(tile[orr+1][oc]);
  ov[2] = f2b(tile[orr+2][oc]); ov[3] = f2b(tile[orr+3][oc]);
  *(short4v*)&out[(size_t)(c0 + oc) * R + r0 + orr] = ov;
}

// ---------------- GEMM: C[M][N] = A[M][K] * Bt[N][K]^T + bias ----------------
// 1-D grid, bijective XCD swizzle (grid divisible by 8): XCD x gets a
// contiguous chunk of tiles -> A row-panels become L2-resident per XCD.
template<int MODE>
__global__ __launch_bounds__(256) void gemm_kernel(
    const short* __restrict__ A, const short* __restrict__ Bt,
    const float* __restrict__ bias, float* __restrict__ Cf,
    short* __restrict__ qo, short* __restrict__ ko2, short* __restrict__ vo,
    int N, int NBX, int cpx) {
  __shared__ short As[4096];
  __shared__ short Bs[4096];
  const int lin = blockIdx.x;
  const int swz = (lin & 7) * cpx + (lin >> 3);
  const int bx = swz % NBX, by = swz / NBX;
  const int tid = threadIdx.x, lane = tid & 63, w = tid >> 6;
  const int rowBase = by * 128, colBase = bx * 128;
  f32x4 acc[4][4] = {};
  const int srow = tid >> 2, sk = (tid & 3) << 3;
  const short* Ag = A  + (size_t)(rowBase + srow) * Kn + sk;
  const short* Bg = Bt + (size_t)(colBase + srow) * Kn + sk;
  short* AsW = As + w * 512;
  short* BsW = Bs + w * 512;
  const int ar = (w >> 1) * 64, bc = (w & 1) * 64;
  const int lg8 = (lane >> 4) * 8, lr = lane & 15;

  for (int kt = 0; kt < Kn; kt += 32) {
    __syncthreads();
    gload16(Ag + kt,            AsW);
    gload16(Ag + kt + 64 * Kn,  AsW + 2048);
    gload16(Bg + kt,            BsW);
    gload16(Bg + kt + 64 * Kn,  BsW + 2048);
    __syncthreads();
    short8 af[4], bfr[4];
#pragma unroll
    for (int m = 0; m < 4; ++m) af[m]  = *(const short8*)&As[(ar + m*16 + lr)*32 + lg8];
#pragma unroll
    for (int n = 0; n < 4; ++n) bfr[n] = *(const short8*)&Bs[(bc + n*16 + lr)*32 + lg8];
#pragma unroll
    for (int m = 0; m < 4; ++m)
#pragma unroll
      for (int n = 0; n < 4; ++n)
        acc[m][n] = mfma16(af[m], bfr[n], acc[m][n]);
  }

  const int gr0 = rowBase + ar + (lane >> 4) * 4;
  const int gc0 = colBase + bc + lr;
#pragma unroll
  for (int m = 0; m < 4; ++m) {
#pragma unroll
    for (int n = 0; n < 4; ++n) {
      const int gc = gc0 + n * 16;
      const float bb = bias[gc];
#pragma unroll
      for (int r = 0; r < 4; ++r) {
        const int gr = gr0 + m * 16 + r;
        const float v = acc[m][n][r] + bb;
        if (MODE == 0) {
          Cf[(size_t)gr * N + gc] = v;
        } else {
          const int which = gc >> 10, e = gc & 1023;
          const int hh = e >> 6, d = e & 63;
          const int bidx = gr >> 11, t = gr & 2047;
          const size_t idx = ((size_t)(bidx * Hn + hh) * Tn + t) * Dh + d;
          short* dst = (which == 0) ? qo : (which == 1) ? ko2 : vo;
          dst[idx] = f2b(v);
        }
      }
    }
  }
}

// ---------------- LayerNorm over D=64; q gets 1/sqrt(D)*log2(e) folded ----------------
__global__ __launch_bounds__(256) void ln_qk_kernel(short* __restrict__ qp, short* __restrict__ kp,
                                                    const float* __restrict__ qg, const float* __restrict__ qb,
                                                    const float* __restrict__ kg, const float* __restrict__ kb) {
  const int lane = threadIdx.x & 63;
  const int rp = blockIdx.x * 4 + (threadIdx.x >> 6);
  const size_t base = (size_t)rp * 64 + lane;
  float xq = b2f(qp[base]);
  float xk = b2f(kp[base]);
  float sq = xq, sk = xk;
#pragma unroll
  for (int off = 1; off < 64; off <<= 1) { sq += __shfl_xor(sq, off); sk += __shfl_xor(sk, off); }
  const float muq = sq * (1.f/64), muk = sk * (1.f/64);
  const float dq = xq - muq, dk = xk - muk;
  float vq = dq * dq, vk = dk * dk;
#pragma unroll
  for (int off = 1; off < 64; off <<= 1) { vq += __shfl_xor(vq, off); vk += __shfl_xor(vk, off); }
  const float rq = rsqrtf(vq * (1.f/64) + 1e-5f);
  const float rk = rsqrtf(vk * (1.f/64) + 1e-5f);
  // fold 1/sqrt(D)=0.125 and log2(e): attention softmax runs in exp2 domain
  const float yq = (dq * rq * qg[lane] + qb[lane]) * (0.125f * 1.44269504088896f);
  const float yk =  dk * rk * kg[lane] + kb[lane];
  qp[base] = f2b(yq);
  kp[base] = f2b(yk);
}

// ---------------- V [bh][t][d] -> Vt [bh][d][t] ----------------
__global__ __launch_bounds__(256) void transpose_v_kernel(const short* __restrict__ vp,
                                                          short* __restrict__ vt) {
  __shared__ short tile[64][72];
  const int tid = threadIdx.x;
  const int bh = blockIdx.y, jt = blockIdx.x;
  const short* src = vp + ((size_t)bh * Tn + jt * 64) * Dh;
#pragma unroll
  for (int i = 0; i < 4; ++i) {
    const int idx = i * 1024 + tid * 4;
    short4v v = *(const short4v*)&src[idx];
    const int r = idx >> 6, c = idx & 63;
    tile[r][c] = v[0]; tile[r][c+1] = v[1]; tile[r][c+2] = v[2]; tile[r][c+3] = v[3];
  }
  __syncthreads();
  short* dst = vt + (size_t)bh * Dh * Tn + jt * 64;
#pragma unroll
  for (int i = 0; i < 4; ++i) {
    const int idx = i * 1024 + tid * 4;
    const int d = idx >> 6, t0 = idx & 63;
    short4v v;
    v[0] = tile[t0][d]; v[1] = tile[t0+1][d]; v[2] = tile[t0+2][d]; v[3] = tile[t0+3][d];
    *(short4v*)&dst[(size_t)d * Tn + t0] = v;
  }
}

// ---------------- Flash attention (round-4 proven 16x16 structure) ----------------
// 1024 blocks (XCD-swizzled -> (bh,qt)), 4 waves, 32 q-rows/wave, KVBLK=64.
// exp2 domain, defer-max, deferred row-sum, truncating P-store, dbuf staging.
__global__ __launch_bounds__(256) void flash_kernel(
    const short* __restrict__ qp, const short* __restrict__ kp,
    const short* __restrict__ vt, short* __restrict__ y) {
  __shared__ short Ks[2][4096];   // [buf][64 keys][64 d]
  __shared__ short Vs[2][4096];   // [buf][64 d][64 keys]
  __shared__ short Ps[8192];      // per-wave 2048 shorts: [32 q][64 k]
  const int tid = threadIdx.x, lane = tid & 63, w = tid >> 6;
  const int lr = lane & 15, lg = lane >> 4;

  // XCD swizzle (bijective): XCD x handles bh in [8x,8x+8), 16 q-tiles each
  const int j0 = blockIdx.x;
  const int xcd = j0 & 7, kk0 = j0 >> 3;
  const int bh = 8 * xcd + (kk0 & 7), qt = kk0 >> 3;

  const int qrow0 = qt * 128 + w * 32;
  const short* qbase = qp + ((size_t)bh * Tn + qrow0) * Dh;

  short8 aq[2][2];
#pragma unroll
  for (int m = 0; m < 2; ++m)
#pragma unroll
    for (int kk = 0; kk < 2; ++kk)
      aq[m][kk] = *(const short8*)&qbase[(m*16 + lr)*64 + kk*32 + lg*8];

  f32x4 o[2][4] = {};
  float mrow[2][4], lpart[2][4];
#pragma unroll
  for (int m = 0; m < 2; ++m)
#pragma unroll
    for (int r = 0; r < 4; ++r) { mrow[m][r] = -3e38f; lpart[m][r] = 0.f; }

  const int srow = tid >> 3;         // 0..31
  const int sc = (tid & 7) * 8;      // shorts
  short* Pw = Ps + w * 2048;
  const short* kb = kp + (size_t)bh * Tn * Dh;
  const short* vb = vt + (size_t)bh * Dh * Tn;

#define STAGE(jt, bsel)                                                   \
  {                                                                       \
    _Pragma("unroll")                                                     \
    for (int i = 0; i < 2; ++i) {                                         \
      const int row = i * 32 + srow;                                      \
      const int scs = sc ^ ((row & 7) << 3);                              \
      gload16(kb + (size_t)((jt) * 64 + row) * Dh + scs,                  \
              &Ks[bsel][w * 512 + i * 2048]);                             \
      gload16(vb + (size_t)row * Tn + (jt) * 64 + scs,                    \
              &Vs[bsel][w * 512 + i * 2048]);                             \
    }                                                                     \
  }

  STAGE(0, 0);
  __syncthreads();

  for (int j = 0; j < Tn / 64; ++j) {
    const int cur = j & 1;
    if (j + 1 < Tn / 64) STAGE(j + 1, cur ^ 1);

    // S = Q K^T  (C: row=q=lg*4+r+16m, col=key=lr+16n)
    short8 bk[4][2];
#pragma unroll
    for (int n = 0; n < 4; ++n)
#pragma unroll
      for (int kk = 0; kk < 2; ++kk) {
        const int row = n * 16 + lr;
        bk[n][kk] = *(const short8*)&Ks[cur][row*64 + ((kk*32 + lg*8) ^ ((row & 7) << 3))];
      }
    f32x4 s[2][4] = {};
    __builtin_amdgcn_s_setprio(1);
#pragma unroll
    for (int m = 0; m < 2; ++m)
#pragma unroll
      for (int n = 0; n < 4; ++n) {
        s[m][n] = mfma16(aq[m][0], bk[n][0], s[m][n]);
        s[m][n] = mfma16(aq[m][1], bk[n][1], s[m][n]);
      }
    __builtin_amdgcn_s_setprio(0);

    // defer-max: per-lane partial max vs stale row max
    float pm[2][4];
#pragma unroll
    for (int m = 0; m < 2; ++m)
#pragma unroll
      for (int r = 0; r < 4; ++r)
        pm[m][r] = fmaxf(fmaxf(s[m][0][r], s[m][1][r]), fmaxf(s[m][2][r], s[m][3][r]));
    int ok = 1;
#pragma unroll
    for (int m = 0; m < 2; ++m)
#pragma unroll
      for (int r = 0; r < 4; ++r)
        ok &= (pm[m][r] <= mrow[m][r] + 11.0f) ? 1 : 0;
    if (!__all(ok)) {
      float tm[2][4];
#pragma unroll
      for (int m = 0; m < 2; ++m)
#pragma unroll
        for (int r = 0; r < 4; ++r) tm[m][r] = pm[m][r];
#pragma unroll
      for (int off = 1; off < 16; off <<= 1)
#pragma unroll
        for (int m = 0; m < 2; ++m)
#pragma unroll
          for (int r = 0; r < 4; ++r)
            tm[m][r] = fmaxf(tm[m][r], __shfl_xor(tm[m][r], off));
#pragma unroll
      for (int m = 0; m < 2; ++m)
#pragma unroll
        for (int r = 0; r < 4; ++r) {
          const float mn = fmaxf(mrow[m][r], tm[m][r]);
          const float corr = __builtin_amdgcn_exp2f(mrow[m][r] - mn);
          lpart[m][r] *= corr;
#pragma unroll
          for (int dn = 0; dn < 4; ++dn) o[m][dn][r] *= corr;
          mrow[m][r] = mn;
        }
    }

    // exp2, accumulate truncated partials, write P (truncated bf16)
#pragma unroll
    for (int m = 0; m < 2; ++m)
#pragma unroll
      for (int n = 0; n < 4; ++n)
#pragma unroll
        for (int r = 0; r < 4; ++r) {
          const float p = __builtin_amdgcn_exp2f(s[m][n][r] - mrow[m][r]);
          const unsigned u = __builtin_bit_cast(unsigned, p);
          lpart[m][r] += __builtin_bit_cast(float, u & 0xffff0000u);
          const int q = m*16 + lg*4 + r;
          const int k = n*16 + lr;
          Pw[q*64 + (k ^ ((q & 7) << 3))] = (short)(u >> 16);
        }

    // O += P V
    short8 pa[2][2], bv[4][2];
#pragma unroll
    for (int m = 0; m < 2; ++m)
#pragma unroll
      for (int kk = 0; kk < 2; ++kk) {
        const int q = m*16 + lr;
        pa[m][kk] = *(const short8*)&Pw[q*64 + ((kk*32 + lg*8) ^ ((q & 7) << 3))];
      }
#pragma unroll
    for (int dn = 0; dn < 4; ++dn)
#pragma unroll
      for (int kk = 0; kk < 2; ++kk) {
        const int row = dn * 16 + lr;
        bv[dn][kk] = *(const short8*)&Vs[cur][row*64 + ((kk*32 + lg*8) ^ ((row & 7) << 3))];
      }
    __builtin_amdgcn_s_setprio(1);
#pragma unroll
    for (int m = 0; m < 2; ++m)
#pragma unroll
      for (int dn = 0; dn < 4; ++dn) {
        o[m][dn] = mfma16(pa[m][0], bv[dn][0], o[m][dn]);
        o[m][dn] = mfma16(pa[m][1], bv[dn][1], o[m][dn]);
      }
    __builtin_amdgcn_s_setprio(0);

    __syncthreads();
  }
#undef STAGE

  // one row-sum tree for the whole kernel
#pragma unroll
  for (int off = 1; off < 16; off <<= 1)
#pragma unroll
    for (int m = 0; m < 2; ++m)
#pragma unroll
      for (int r = 0; r < 4; ++r)
        lpart[m][r] += __shfl_xor(lpart[m][r], off);

  // normalize + store y[B][T][E] bf16
  const int b = bh >> 4, hh = bh & 15;
  short* yb = y + (size_t)b * Tn * En + hh * 64;
#pragma unroll
  for (int m = 0; m < 2; ++m)
#pragma unroll
    for (int r = 0; r < 4; ++r) {
      const float rl = 1.0f / lpart[m][r];
      const int t = qrow0 + m*16 + lg*4 + r;
#pragma unroll
      for (int dn = 0; dn < 4; ++dn) {
        const int d = dn*16 + lr;
        yb[(size_t)t * En + d] = f2b(o[m][dn][r] * rl);
      }
    }
}

extern "C" void kernel_launch(void* const* d_in, const int* in_sizes, int n_in,
                              void* d_out, int out_size, void* d_ws, size_t ws_size,
                              hipStream_t stream) {
  const float* x     = (const float*)d_in[0];
  const float* Wqkv  = (const float*)d_in[1];
  const float* bqkv  = (const float*)d_in[2];
  const float* qg    = (const float*)d_in[3];
  const float* qb    = (const float*)d_in[4];
  const float* kg    = (const float*)d_in[5];
  const float* kb    = (const float*)d_in[6];
  const float* Wproj = (const float*)d_in[7];
  const float* bproj = (const float*)d_in[8];
  float* out = (float*)d_out;

  char* p = (char*)d_ws;
  short* xb     = (short*)p; p += (size_t)Mn * Kn * 2;
  short* wqkvT  = (short*)p; p += (size_t)N1 * Kn * 2;
  short* wprojT = (short*)p; p += (size_t)En * Kn * 2;
  short* qp     = (short*)p; p += (size_t)Mn * Kn * 2;
  short* kp     = (short*)p; p += (size_t)Mn * Kn * 2;
  short* vp     = (short*)p; p += (size_t)Mn * Kn * 2;
  short* vtb    = (short*)p; p += (size_t)Mn * Kn * 2;
  short* yb     = (short*)p; p += (size_t)Mn * Kn * 2;

  cvt_x_kernel<<<Mn * Kn / (256 * 8), 256, 0, stream>>>(x, xb);
  transpose_w_kernel<<<dim3(N1 / 32, Kn / 32), 256, 0, stream>>>(Wqkv, wqkvT, Kn, N1);
  transpose_w_kernel<<<dim3(En / 32, Kn / 32), 256, 0, stream>>>(Wproj, wprojT, Kn, En);
  // GEMM1: 24x64 tiles = 1536 blocks (divisible by 8)
  gemm_kernel<1><<<(N1 / 128) * (Mn / 128), 256, 0, stream>>>(
      xb, wqkvT, bqkv, nullptr, qp, kp, vp, N1, N1 / 128, (N1 / 128) * (Mn / 128) / 8);
  ln_qk_kernel<<<BHT / 4, 256, 0, stream>>>(qp, kp, qg, qb, kg, kb);
  transpose_v_kernel<<<dim3(Tn / 64, Bb * Hn), 256, 0, stream>>>(vp, vtb);
  flash_kernel<<<1024, 256, 0, stream>>>(qp, kp, vtb, yb);
  // GEMM2: 8x64 tiles = 512 blocks (divisible by 8)
  gemm_kernel<0><<<(En / 128) * (Mn / 128), 256, 0, stream>>>(
      yb, wprojT, bproj, out, nullptr, nullptr, nullptr, En, En / 128, (En / 128) * (Mn / 128) / 8);
}

// Round 7
// 285.862 us; speedup vs baseline: 1.4786x; 1.0141x over previous
//
#include <hip/hip_runtime.h>

// Problem constants
#define Hn  16
#define Dh  64
#define Bb  4
#define Tn  2048
#define En  1024
#define Mn  8192           // B*T
#define N1  3072           // 3*E
#define Kn  1024           // E
#define BHT (Bb*Hn*Tn)     // 262144

typedef __attribute__((ext_vector_type(8)))  short  short8;
typedef __attribute__((ext_vector_type(4)))  short  short4v;
typedef __attribute__((ext_vector_type(4)))  float  f32x4;
typedef __attribute__((ext_vector_type(8)))  __bf16 bf16x8;

__device__ __forceinline__ float b2f(short s) {
  unsigned u = ((unsigned)(unsigned short)s) << 16;
  return __builtin_bit_cast(float, u);
}
__device__ __forceinline__ short f2b(float f) {
  unsigned u = __builtin_bit_cast(unsigned, f);
  u += 0x7fffu + ((u >> 16) & 1u);
  return (short)(u >> 16);
}
__device__ __forceinline__ f32x4 mfma16(short8 a, short8 b, f32x4 c) {
  return __builtin_amdgcn_mfma_f32_16x16x32_bf16(
      __builtin_bit_cast(bf16x8, a), __builtin_bit_cast(bf16x8, b), c, 0, 0, 0);
}
__device__ __forceinline__ void gload16(const void* g, void* l) {
  __builtin_amdgcn_global_load_lds(
      (const __attribute__((address_space(1))) unsigned int*)g,
      (__attribute__((address_space(3))) unsigned int*)l, 16, 0, 0);
}

// ---------------- cast x -> bf16 ----------------
__global__ __launch_bounds__(256) void cvt_x_kernel(const float* __restrict__ x,
                                                    short* __restrict__ xb) {
  const size_t i = ((size_t)blockIdx.x * 256 + threadIdx.x) * 8;
  f32x4 a = *(const f32x4*)&x[i];
  f32x4 b = *(const f32x4*)&x[i + 4];
  short8 o;
  o[0]=f2b(a[0]); o[1]=f2b(a[1]); o[2]=f2b(a[2]); o[3]=f2b(a[3]);
  o[4]=f2b(b[0]); o[5]=f2b(b[1]); o[6]=f2b(b[2]); o[7]=f2b(b[3]);
  *(short8*)&xb[i] = o;
}

// ---------------- transpose W [R][C] f32 -> [C][R] bf16 ----------------
__global__ __launch_bounds__(256) void transpose_w_kernel(const float* __restrict__ in,
                                                          short* __restrict__ out,
                                                          int R, int C) {
  __shared__ float tile[32][33];
  const int tid = threadIdx.x;
  const int c0 = blockIdx.x * 32, r0 = blockIdx.y * 32;
  const int lr = tid >> 3, lc = (tid & 7) * 4;
  f32x4 v = *(const f32x4*)&in[(size_t)(r0 + lr) * C + c0 + lc];
  tile[lr][lc] = v[0]; tile[lr][lc+1] = v[1]; tile[lr][lc+2] = v[2]; tile[lr][lc+3] = v[3];
  __syncthreads();
  const int oc = tid >> 3, orr = (tid & 7) * 4;
  short4v ov;
  ov[0] = f2b(tile[orr][oc]);   ov[1] = f2b(tile[orr+1][oc]);
  ov[2] = f2b(tile[orr+2][oc]); ov[3] = f2b(tile[orr+3][oc]);
  *(short4v*)&out[(size_t)(c0 + oc) * R + r0 + orr] = ov;
}

// ---------------- GEMM: C[M][N] = A[M][K] * Bt[N][K]^T + bias ----------------
// 1-D grid, bijective XCD swizzle (grid divisible by 8).
template<int MODE>
__global__ __launch_bounds__(256) void gemm_kernel(
    const short* __restrict__ A, const short* __restrict__ Bt,
    const float* __restrict__ bias, float* __restrict__ Cf,
    short* __restrict__ qo, short* __restrict__ ko2, short* __restrict__ vo,
    int N, int NBX, int cpx) {
  __shared__ short As[4096];
  __shared__ short Bs[4096];
  const int lin = blockIdx.x;
  const int swz = (lin & 7) * cpx + (lin >> 3);
  const int bx = swz % NBX, by = swz / NBX;
  const int tid = threadIdx.x, lane = tid & 63, w = tid >> 6;
  const int rowBase = by * 128, colBase = bx * 128;
  f32x4 acc[4][4] = {};
  const int srow = tid >> 2, sk = (tid & 3) << 3;
  const short* Ag = A  + (size_t)(rowBase + srow) * Kn + sk;
  const short* Bg = Bt + (size_t)(colBase + srow) * Kn + sk;
  short* AsW = As + w * 512;
  short* BsW = Bs + w * 512;
  const int ar = (w >> 1) * 64, bc = (w & 1) * 64;
  const int lg8 = (lane >> 4) * 8, lr = lane & 15;

  for (int kt = 0; kt < Kn; kt += 32) {
    __syncthreads();
    gload16(Ag + kt,            AsW);
    gload16(Ag + kt + 64 * Kn,  AsW + 2048);
    gload16(Bg + kt,            BsW);
    gload16(Bg + kt + 64 * Kn,  BsW + 2048);
    __syncthreads();
    short8 af[4], bfr[4];
#pragma unroll
    for (int m = 0; m < 4; ++m) af[m]  = *(const short8*)&As[(ar + m*16 + lr)*32 + lg8];
#pragma unroll
    for (int n = 0; n < 4; ++n) bfr[n] = *(const short8*)&Bs[(bc + n*16 + lr)*32 + lg8];
#pragma unroll
    for (int m = 0; m < 4; ++m)
#pragma unroll
      for (int n = 0; n < 4; ++n)
        acc[m][n] = mfma16(af[m], bfr[n], acc[m][n]);
  }

  const int gr0 = rowBase + ar + (lane >> 4) * 4;
  const int gc0 = colBase + bc + lr;
#pragma unroll
  for (int m = 0; m < 4; ++m) {
#pragma unroll
    for (int n = 0; n < 4; ++n) {
      const int gc = gc0 + n * 16;
      const float bb = bias[gc];
#pragma unroll
      for (int r = 0; r < 4; ++r) {
        const int gr = gr0 + m * 16 + r;
        const float v = acc[m][n][r] + bb;
        if (MODE == 0) {
          Cf[(size_t)gr * N + gc] = v;
        } else {
          const int which = gc >> 10, e = gc & 1023;
          const int hh = e >> 6, d = e & 63;
          const int bidx = gr >> 11, t = gr & 2047;
          const size_t idx = ((size_t)(bidx * Hn + hh) * Tn + t) * Dh + d;
          short* dst = (which == 0) ? qo : (which == 1) ? ko2 : vo;
          dst[idx] = f2b(v);
        }
      }
    }
  }
}

// ---------------- LayerNorm over D=64; q gets 1/sqrt(D)*log2(e) folded ----------------
__global__ __launch_bounds__(256) void ln_qk_kernel(short* __restrict__ qp, short* __restrict__ kp,
                                                    const float* __restrict__ qg, const float* __restrict__ qb,
                                                    const float* __restrict__ kg, const float* __restrict__ kb) {
  const int lane = threadIdx.x & 63;
  const int rp = blockIdx.x * 4 + (threadIdx.x >> 6);
  const size_t base = (size_t)rp * 64 + lane;
  float xq = b2f(qp[base]);
  float xk = b2f(kp[base]);
  float sq = xq, sk = xk;
#pragma unroll
  for (int off = 1; off < 64; off <<= 1) { sq += __shfl_xor(sq, off); sk += __shfl_xor(sk, off); }
  const float muq = sq * (1.f/64), muk = sk * (1.f/64);
  const float dq = xq - muq, dk = xk - muk;
  float vq = dq * dq, vk = dk * dk;
#pragma unroll
  for (int off = 1; off < 64; off <<= 1) { vq += __shfl_xor(vq, off); vk += __shfl_xor(vk, off); }
  const float rq = rsqrtf(vq * (1.f/64) + 1e-5f);
  const float rk = rsqrtf(vk * (1.f/64) + 1e-5f);
  // fold 1/sqrt(D)=0.125 and log2(e): attention softmax runs in exp2 domain
  const float yq = (dq * rq * qg[lane] + qb[lane]) * (0.125f * 1.44269504088896f);
  const float yk =  dk * rk * kg[lane] + kb[lane];
  qp[base] = f2b(yq);
  kp[base] = f2b(yk);
}

// ---------------- V [bh][t][d] -> Vt [bh][d][t] ----------------
__global__ __launch_bounds__(256) void transpose_v_kernel(const short* __restrict__ vp,
                                                          short* __restrict__ vt) {
  __shared__ short tile[64][72];
  const int tid = threadIdx.x;
  const int bh = blockIdx.y, jt = blockIdx.x;
  const short* src = vp + ((size_t)bh * Tn + jt * 64) * Dh;
#pragma unroll
  for (int i = 0; i < 4; ++i) {
    const int idx = i * 1024 + tid * 4;
    short4v v = *(const short4v*)&src[idx];
    const int r = idx >> 6, c = idx & 63;
    tile[r][c] = v[0]; tile[r][c+1] = v[1]; tile[r][c+2] = v[2]; tile[r][c+3] = v[3];
  }
  __syncthreads();
  short* dst = vt + (size_t)bh * Dh * Tn + jt * 64;
#pragma unroll
  for (int i = 0; i < 4; ++i) {
    const int idx = i * 1024 + tid * 4;
    const int d = idx >> 6, t0 = idx & 63;
    short4v v;
    v[0] = tile[t0][d]; v[1] = tile[t0+1][d]; v[2] = tile[t0+2][d]; v[3] = tile[t0+3][d];
    *(short4v*)&dst[(size_t)d * Tn + t0] = v;
  }
}

// ---------------- Flash attention (proven 16x16 structure) ----------------
// 1024 blocks (XCD-swizzled), 4 waves, 32 q-rows/wave, KVBLK=64.
// Round-7 changes (layout-safe): (1) P staged through a half-size per-wave
// [32q][32k] buffer in two sequential phases (LDS 48->40KB, 4 blocks/CU;
// within-wave DS ordering makes the buffer reuse safe); (2) row-sum via
// ones-MFMA into lacc (exact bf16 bias cancellation, no per-element VALU,
// no epilogue shuffle tree).
__global__ __launch_bounds__(256) void flash_kernel(
    const short* __restrict__ qp, const short* __restrict__ kp,
    const short* __restrict__ vt, short* __restrict__ y) {
  __shared__ short Ks[2][4096];   // [buf][64 keys][64 d]
  __shared__ short Vs[2][4096];   // [buf][64 d][64 keys]
  __shared__ short Ps[4096];      // per-wave 1024 shorts: [32 q][32 k] half-tile
  const int tid = threadIdx.x, lane = tid & 63, w = tid >> 6;
  const int lr = lane & 15, lg = lane >> 4;

  // XCD swizzle (bijective): XCD x handles bh in [8x,8x+8), 16 q-tiles each
  const int j0 = blockIdx.x;
  const int xcd = j0 & 7, kk0 = j0 >> 3;
  const int bh = 8 * xcd + (kk0 & 7), qt = kk0 >> 3;

  const int qrow0 = qt * 128 + w * 32;
  const short* qbase = qp + ((size_t)bh * Tn + qrow0) * Dh;

  short8 aq[2][2];
#pragma unroll
  for (int m = 0; m < 2; ++m)
#pragma unroll
    for (int kk = 0; kk < 2; ++kk)
      aq[m][kk] = *(const short8*)&qbase[(m*16 + lr)*64 + kk*32 + lg*8];

  short8 ones;
#pragma unroll
  for (int i = 0; i < 8; ++i) ones[i] = (short)0x3F80;   // bf16 1.0

  f32x4 o[2][4] = {};
  f32x4 lacc[2] = {};             // row sums via ones-MFMA (C-layout = mrow layout)
  float mrow[2][4];
#pragma unroll
  for (int m = 0; m < 2; ++m)
#pragma unroll
    for (int r = 0; r < 4; ++r) mrow[m][r] = -3e38f;

  const int srow = tid >> 3;         // 0..31
  const int sc = (tid & 7) * 8;      // shorts
  short* Pw = Ps + w * 1024;
  const short* kb = kp + (size_t)bh * Tn * Dh;
  const short* vb = vt + (size_t)bh * Dh * Tn;

#define STAGE(jt, bsel)                                                   \
  {                                                                       \
    _Pragma("unroll")                                                     \
    for (int i = 0; i < 2; ++i) {                                         \
      const int row = i * 32 + srow;                                      \
      const int scs = sc ^ ((row & 7) << 3);                              \
      gload16(kb + (size_t)((jt) * 64 + row) * Dh + scs,                  \
              &Ks[bsel][w * 512 + i * 2048]);                             \
      gload16(vb + (size_t)row * Tn + (jt) * 64 + scs,                    \
              &Vs[bsel][w * 512 + i * 2048]);                             \
    }                                                                     \
  }

// P swizzle: 8-short granular, bijective within a 32-short row
#define PSW(q) ((((q) & 3) << 3) ^ (((q) & 4) << 2))

  STAGE(0, 0);
  __syncthreads();

  for (int j = 0; j < Tn / 64; ++j) {
    const int cur = j & 1;
    if (j + 1 < Tn / 64) STAGE(j + 1, cur ^ 1);

    // S = Q K^T  (C: row=q=lg*4+r+16m, col=key=lr+16n)
    short8 bk[4][2];
#pragma unroll
    for (int n = 0; n < 4; ++n)
#pragma unroll
      for (int kk = 0; kk < 2; ++kk) {
        const int row = n * 16 + lr;
        bk[n][kk] = *(const short8*)&Ks[cur][row*64 + ((kk*32 + lg*8) ^ ((row & 7) << 3))];
      }
    f32x4 s[2][4] = {};
    __builtin_amdgcn_s_setprio(1);
#pragma unroll
    for (int m = 0; m < 2; ++m)
#pragma unroll
      for (int n = 0; n < 4; ++n) {
        s[m][n] = mfma16(aq[m][0], bk[n][0], s[m][n]);
        s[m][n] = mfma16(aq[m][1], bk[n][1], s[m][n]);
      }
    __builtin_amdgcn_s_setprio(0);

    // defer-max: per-lane partial max vs stale row max
    float pm[2][4];
#pragma unroll
    for (int m = 0; m < 2; ++m)
#pragma unroll
      for (int r = 0; r < 4; ++r)
        pm[m][r] = fmaxf(fmaxf(s[m][0][r], s[m][1][r]), fmaxf(s[m][2][r], s[m][3][r]));
    int ok = 1;
#pragma unroll
    for (int m = 0; m < 2; ++m)
#pragma unroll
      for (int r = 0; r < 4; ++r)
        ok &= (pm[m][r] <= mrow[m][r] + 11.0f) ? 1 : 0;
    if (!__all(ok)) {
      float tm[2][4];
#pragma unroll
      for (int m = 0; m < 2; ++m)
#pragma unroll
        for (int r = 0; r < 4; ++r) tm[m][r] = pm[m][r];
#pragma unroll
      for (int off = 1; off < 16; off <<= 1)
#pragma unroll
        for (int m = 0; m < 2; ++m)
#pragma unroll
          for (int r = 0; r < 4; ++r)
            tm[m][r] = fmaxf(tm[m][r], __shfl_xor(tm[m][r], off));
#pragma unroll
      for (int m = 0; m < 2; ++m)
#pragma unroll
        for (int r = 0; r < 4; ++r) {
          const float mn = fmaxf(mrow[m][r], tm[m][r]);
          const float corr = __builtin_amdgcn_exp2f(mrow[m][r] - mn);
          lacc[m][r] *= corr;
#pragma unroll
          for (int dn = 0; dn < 4; ++dn) o[m][dn][r] *= corr;
          mrow[m][r] = mn;
        }
    }

    // V fragments (independent of P phases)
    short8 bv[4][2];
#pragma unroll
    for (int dn = 0; dn < 4; ++dn)
#pragma unroll
      for (int kk = 0; kk < 2; ++kk) {
        const int row = dn * 16 + lr;
        bv[dn][kk] = *(const short8*)&Vs[cur][row*64 + ((kk*32 + lg*8) ^ ((row & 7) << 3))];
      }

    // ---- phase 0: keys 0..31 (n=0,1) ----
#pragma unroll
    for (int m = 0; m < 2; ++m)
#pragma unroll
      for (int n = 0; n < 2; ++n)
#pragma unroll
        for (int r = 0; r < 4; ++r) {
          const float p = __builtin_amdgcn_exp2f(s[m][n][r] - mrow[m][r]);
          const unsigned u = __builtin_bit_cast(unsigned, p);
          const int q = m*16 + lg*4 + r;
          Pw[q*32 + ((n*16 + lr) ^ PSW(q))] = (short)(u >> 16);
        }
    short8 pa0[2];
#pragma unroll
    for (int m = 0; m < 2; ++m) {
      const int q = m*16 + lr;
      pa0[m] = *(const short8*)&Pw[q*32 + ((lg*8) ^ PSW(q))];
    }
    __builtin_amdgcn_s_setprio(1);
#pragma unroll
    for (int m = 0; m < 2; ++m) {
      lacc[m] = mfma16(pa0[m], ones, lacc[m]);
#pragma unroll
      for (int dn = 0; dn < 4; ++dn)
        o[m][dn] = mfma16(pa0[m], bv[dn][0], o[m][dn]);
    }
    __builtin_amdgcn_s_setprio(0);

    // ---- phase 1: keys 32..63 (n=2,3), same buffer (in-order DS) ----
#pragma unroll
    for (int m = 0; m < 2; ++m)
#pragma unroll
      for (int n = 0; n < 2; ++n)
#pragma unroll
        for (int r = 0; r < 4; ++r) {
          const float p = __builtin_amdgcn_exp2f(s[m][2 + n][r] - mrow[m][r]);
          const unsigned u = __builtin_bit_cast(unsigned, p);
          const int q = m*16 + lg*4 + r;
          Pw[q*32 + ((n*16 + lr) ^ PSW(q))] = (short)(u >> 16);
        }
    short8 pa1[2];
#pragma unroll
    for (int m = 0; m < 2; ++m) {
      const int q = m*16 + lr;
      pa1[m] = *(const short8*)&Pw[q*32 + ((lg*8) ^ PSW(q))];
    }
    __builtin_amdgcn_s_setprio(1);
#pragma unroll
    for (int m = 0; m < 2; ++m) {
      lacc[m] = mfma16(pa1[m], ones, lacc[m]);
#pragma unroll
      for (int dn = 0; dn < 4; ++dn)
        o[m][dn] = mfma16(pa1[m], bv[dn][1], o[m][dn]);
    }
    __builtin_amdgcn_s_setprio(0);

    __syncthreads();
  }
#undef STAGE
#undef PSW

  // normalize + store y[B][T][E] bf16 (lacc already holds full row sums)
  const int b = bh >> 4, hh = bh & 15;
  short* yb = y + (size_t)b * Tn * En + hh * 64;
#pragma unroll
  for (int m = 0; m < 2; ++m)
#pragma unroll
    for (int r = 0; r < 4; ++r) {
      const float rl = 1.0f / lacc[m][r];
      const int t = qrow0 + m*16 + lg*4 + r;
#pragma unroll
      for (int dn = 0; dn < 4; ++dn) {
        const int d = dn*16 + lr;
        yb[(size_t)t * En + d] = f2b(o[m][dn][r] * rl);
      }
    }
}

extern "C" void kernel_launch(void* const* d_in, const int* in_sizes, int n_in,
                              void* d_out, int out_size, void* d_ws, size_t ws_size,
                              hipStream_t stream) {
  const float* x     = (const float*)d_in[0];
  const float* Wqkv  = (const float*)d_in[1];
  const float* bqkv  = (const float*)d_in[2];
  const float* qg    = (const float*)d_in[3];
  const float* qb    = (const float*)d_in[4];
  const float* kg    = (const float*)d_in[5];
  const float* kb    = (const float*)d_in[6];
  const float* Wproj = (const float*)d_in[7];
  const float* bproj = (const float*)d_in[8];
  float* out = (float*)d_out;

  char* p = (char*)d_ws;
  short* xb     = (short*)p; p += (size_t)Mn * Kn * 2;
  short* wqkvT  = (short*)p; p += (size_t)N1 * Kn * 2;
  short* wprojT = (short*)p; p += (size_t)En * Kn * 2;
  short* qp     = (short*)p; p += (size_t)Mn * Kn * 2;
  short* kp     = (short*)p; p += (size_t)Mn * Kn * 2;
  short* vp     = (short*)p; p += (size_t)Mn * Kn * 2;
  short* vtb    = (short*)p; p += (size_t)Mn * Kn * 2;
  short* yb     = (short*)p; p += (size_t)Mn * Kn * 2;

  cvt_x_kernel<<<Mn * Kn / (256 * 8), 256, 0, stream>>>(x, xb);
  transpose_w_kernel<<<dim3(N1 / 32, Kn / 32), 256, 0, stream>>>(Wqkv, wqkvT, Kn, N1);
  transpose_w_kernel<<<dim3(En / 32, Kn / 32), 256, 0, stream>>>(Wproj, wprojT, Kn, En);
  gemm_kernel<1><<<(N1 / 128) * (Mn / 128), 256, 0, stream>>>(
      xb, wqkvT, bqkv, nullptr, qp, kp, vp, N1, N1 / 128, (N1 / 128) * (Mn / 128) / 8);
  ln_qk_kernel<<<BHT / 4, 256, 0, stream>>>(qp, kp, qg, qb, kg, kb);
  transpose_v_kernel<<<dim3(Tn / 64, Bb * Hn), 256, 0, stream>>>(vp, vtb);
  flash_kernel<<<1024, 256, 0, stream>>>(qp, kp, vtb, yb);
  gemm_kernel<0><<<(En / 128) * (Mn / 128), 256, 0, stream>>>(
      yb, wprojT, bproj, out, nullptr, nullptr, nullptr, En, En / 128, (En / 128) * (Mn / 128) / 8);
}

// Round 8
// 264.454 us; speedup vs baseline: 1.5983x; 1.0810x over previous
//
#include <hip/hip_runtime.h>

// Problem constants
#define Hn  16
#define Dh  64
#define Bb  4
#define Tn  2048
#define En  1024
#define Mn  8192           // B*T
#define N1  3072           // 3*E
#define Kn  1024           // E
#define BHT (Bb*Hn*Tn)     // 262144

typedef __attribute__((ext_vector_type(8)))  short  short8;
typedef __attribute__((ext_vector_type(4)))  short  short4v;
typedef __attribute__((ext_vector_type(4)))  float  f32x4;
typedef __attribute__((ext_vector_type(8)))  __bf16 bf16x8;

__device__ __forceinline__ float b2f(short s) {
  unsigned u = ((unsigned)(unsigned short)s) << 16;
  return __builtin_bit_cast(float, u);
}
__device__ __forceinline__ short f2b(float f) {
  unsigned u = __builtin_bit_cast(unsigned, f);
  u += 0x7fffu + ((u >> 16) & 1u);
  return (short)(u >> 16);
}
__device__ __forceinline__ f32x4 mfma16(short8 a, short8 b, f32x4 c) {
  return __builtin_amdgcn_mfma_f32_16x16x32_bf16(
      __builtin_bit_cast(bf16x8, a), __builtin_bit_cast(bf16x8, b), c, 0, 0, 0);
}
__device__ __forceinline__ void gload16(const void* g, void* l) {
  __builtin_amdgcn_global_load_lds(
      (const __attribute__((address_space(1))) unsigned int*)g,
      (__attribute__((address_space(3))) unsigned int*)l, 16, 0, 0);
}

// ---------------- cast x -> bf16 ----------------
__global__ __launch_bounds__(256) void cvt_x_kernel(const float* __restrict__ x,
                                                    short* __restrict__ xb) {
  const size_t i = ((size_t)blockIdx.x * 256 + threadIdx.x) * 8;
  f32x4 a = *(const f32x4*)&x[i];
  f32x4 b = *(const f32x4*)&x[i + 4];
  short8 o;
  o[0]=f2b(a[0]); o[1]=f2b(a[1]); o[2]=f2b(a[2]); o[3]=f2b(a[3]);
  o[4]=f2b(b[0]); o[5]=f2b(b[1]); o[6]=f2b(b[2]); o[7]=f2b(b[3]);
  *(short8*)&xb[i] = o;
}

// ---------------- transpose W [R][C] f32 -> [C][R] bf16 ----------------
__global__ __launch_bounds__(256) void transpose_w_kernel(const float* __restrict__ in,
                                                          short* __restrict__ out,
                                                          int R, int C) {
  __shared__ float tile[32][33];
  const int tid = threadIdx.x;
  const int c0 = blockIdx.x * 32, r0 = blockIdx.y * 32;
  const int lr = tid >> 3, lc = (tid & 7) * 4;
  f32x4 v = *(const f32x4*)&in[(size_t)(r0 + lr) * C + c0 + lc];
  tile[lr][lc] = v[0]; tile[lr][lc+1] = v[1]; tile[lr][lc+2] = v[2]; tile[lr][lc+3] = v[3];
  __syncthreads();
  const int oc = tid >> 3, orr = (tid & 7) * 4;
  short4v ov;
  ov[0] = f2b(tile[orr][oc]);   ov[1] = f2b(tile[orr+1][oc]);
  ov[2] = f2b(tile[orr+2][oc]); ov[3] = f2b(tile[orr+3][oc]);
  *(short4v*)&out[(size_t)(c0 + oc) * R + r0 + orr] = ov;
}

// ---------------- GEMM: C[M][N] = A[M][K] * Bt[N][K]^T + bias ----------------
// 1-D grid, bijective XCD swizzle (grid divisible by 8).
// MODE 0: fp32 out to Cf.
// MODE 1: QKV producer. which = colBase>>10 is BLOCK-uniform (128-wide,
//   1024-aligned col tiles). q/k blocks apply fused LayerNorm over D=64
//   on the fp32 accumulators (per row: 4 in-lane regs x 16 same-lg lanes,
//   shfl_xor 1/2/4/8), q additionally scaled by 0.125*log2e. v blocks
//   store directly TRANSPOSED to [bh][d][t] (epilogue is scatter anyway).
template<int MODE>
__global__ __launch_bounds__(256) void gemm_kernel(
    const short* __restrict__ A, const short* __restrict__ Bt,
    const float* __restrict__ bias, float* __restrict__ Cf,
    short* __restrict__ qo, short* __restrict__ ko2, short* __restrict__ vo,
    const float* __restrict__ qg, const float* __restrict__ qb,
    const float* __restrict__ kg, const float* __restrict__ kb,
    int N, int NBX, int cpx) {
  __shared__ short As[4096];
  __shared__ short Bs[4096];
  const int lin = blockIdx.x;
  const int swz = (lin & 7) * cpx + (lin >> 3);
  const int bx = swz % NBX, by = swz / NBX;
  const int tid = threadIdx.x, lane = tid & 63, w = tid >> 6;
  const int rowBase = by * 128, colBase = bx * 128;
  f32x4 acc[4][4] = {};
  const int srow = tid >> 2, sk = (tid & 3) << 3;
  const short* Ag = A  + (size_t)(rowBase + srow) * Kn + sk;
  const short* Bg = Bt + (size_t)(colBase + srow) * Kn + sk;
  short* AsW = As + w * 512;
  short* BsW = Bs + w * 512;
  const int ar = (w >> 1) * 64, bc = (w & 1) * 64;
  const int lg8 = (lane >> 4) * 8, lr = lane & 15;

  for (int kt = 0; kt < Kn; kt += 32) {
    __syncthreads();
    gload16(Ag + kt,            AsW);
    gload16(Ag + kt + 64 * Kn,  AsW + 2048);
    gload16(Bg + kt,            BsW);
    gload16(Bg + kt + 64 * Kn,  BsW + 2048);
    __syncthreads();
    short8 af[4], bfr[4];
#pragma unroll
    for (int m = 0; m < 4; ++m) af[m]  = *(const short8*)&As[(ar + m*16 + lr)*32 + lg8];
#pragma unroll
    for (int n = 0; n < 4; ++n) bfr[n] = *(const short8*)&Bs[(bc + n*16 + lr)*32 + lg8];
#pragma unroll
    for (int m = 0; m < 4; ++m)
#pragma unroll
      for (int n = 0; n < 4; ++n)
        acc[m][n] = mfma16(af[m], bfr[n], acc[m][n]);
  }

  const int gr0 = rowBase + ar + (lane >> 4) * 4;
  const int gc0 = colBase + bc + lr;

  // bias add (before LN, per reference)
  float bb[4];
#pragma unroll
  for (int n = 0; n < 4; ++n) bb[n] = bias[gc0 + n * 16];
#pragma unroll
  for (int m = 0; m < 4; ++m)
#pragma unroll
    for (int n = 0; n < 4; ++n)
#pragma unroll
      for (int r = 0; r < 4; ++r) acc[m][n][r] += bb[n];

  if (MODE == 1) {
    const int which = colBase >> 10;            // block-uniform: 0=q 1=k 2=v
    if (which < 2) {
      const float* gp = (which == 0) ? qg : kg;
      const float* bp = (which == 0) ? qb : kb;
      const float sc = (which == 0) ? 0.1803368801111204f : 1.0f;  // 0.125*log2(e)
      float gam[4], bet[4];
#pragma unroll
      for (int n = 0; n < 4; ++n) { gam[n] = gp[n * 16 + lr]; bet[n] = bp[n * 16 + lr]; }
#pragma unroll
      for (int m = 0; m < 4; ++m)
#pragma unroll
        for (int r = 0; r < 4; ++r) {
          float s1 = 0.f, s2 = 0.f;
#pragma unroll
          for (int n = 0; n < 4; ++n) {
            const float v = acc[m][n][r];
            s1 += v; s2 += v * v;
          }
#pragma unroll
          for (int off = 1; off < 16; off <<= 1) {
            s1 += __shfl_xor(s1, off);
            s2 += __shfl_xor(s2, off);
          }
          const float mu = s1 * 0.015625f;
          const float rs = rsqrtf(s2 * 0.015625f - mu * mu + 1e-5f);
#pragma unroll
          for (int n = 0; n < 4; ++n)
            acc[m][n][r] = ((acc[m][n][r] - mu) * rs * gam[n] + bet[n]) * sc;
        }
    }
  }

#pragma unroll
  for (int m = 0; m < 4; ++m) {
#pragma unroll
    for (int n = 0; n < 4; ++n) {
      const int gc = gc0 + n * 16;
#pragma unroll
      for (int r = 0; r < 4; ++r) {
        const int gr = gr0 + m * 16 + r;
        const float v = acc[m][n][r];
        if (MODE == 0) {
          Cf[(size_t)gr * N + gc] = v;
        } else {
          const int which = gc >> 10, e = gc & 1023;
          const int hh = e >> 6, d = e & 63;
          const int bidx = gr >> 11, t = gr & 2047;
          const int bh = bidx * Hn + hh;
          if (which == 0) {
            qo[((size_t)bh * Tn + t) * Dh + d] = f2b(v);
          } else if (which == 1) {
            ko2[((size_t)bh * Tn + t) * Dh + d] = f2b(v);
          } else {
            vo[((size_t)bh * Dh + d) * Tn + t] = f2b(v);   // transposed [bh][d][t]
          }
        }
      }
    }
  }
}

// ---------------- Flash attention (proven round-7 kernel, unchanged) ----------------
__global__ __launch_bounds__(256) void flash_kernel(
    const short* __restrict__ qp, const short* __restrict__ kp,
    const short* __restrict__ vt, short* __restrict__ y) {
  __shared__ short Ks[2][4096];   // [buf][64 keys][64 d]
  __shared__ short Vs[2][4096];   // [buf][64 d][64 keys]
  __shared__ short Ps[4096];      // per-wave 1024 shorts: [32 q][32 k] half-tile
  const int tid = threadIdx.x, lane = tid & 63, w = tid >> 6;
  const int lr = lane & 15, lg = lane >> 4;

  // XCD swizzle (bijective): XCD x handles bh in [8x,8x+8), 16 q-tiles each
  const int j0 = blockIdx.x;
  const int xcd = j0 & 7, kk0 = j0 >> 3;
  const int bh = 8 * xcd + (kk0 & 7), qt = kk0 >> 3;

  const int qrow0 = qt * 128 + w * 32;
  const short* qbase = qp + ((size_t)bh * Tn + qrow0) * Dh;

  short8 aq[2][2];
#pragma unroll
  for (int m = 0; m < 2; ++m)
#pragma unroll
    for (int kk = 0; kk < 2; ++kk)
      aq[m][kk] = *(const short8*)&qbase[(m*16 + lr)*64 + kk*32 + lg*8];

  short8 ones;
#pragma unroll
  for (int i = 0; i < 8; ++i) ones[i] = (short)0x3F80;   // bf16 1.0

  f32x4 o[2][4] = {};
  f32x4 lacc[2] = {};             // row sums via ones-MFMA (C-layout = mrow layout)
  float mrow[2][4];
#pragma unroll
  for (int m = 0; m < 2; ++m)
#pragma unroll
    for (int r = 0; r < 4; ++r) mrow[m][r] = -3e38f;

  const int srow = tid >> 3;         // 0..31
  const int sc = (tid & 7) * 8;      // shorts
  short* Pw = Ps + w * 1024;
  const short* kb = kp + (size_t)bh * Tn * Dh;
  const short* vb = vt + (size_t)bh * Dh * Tn;

#define STAGE(jt, bsel)                                                   \
  {                                                                       \
    _Pragma("unroll")                                                     \
    for (int i = 0; i < 2; ++i) {                                         \
      const int row = i * 32 + srow;                                      \
      const int scs = sc ^ ((row & 7) << 3);                              \
      gload16(kb + (size_t)((jt) * 64 + row) * Dh + scs,                  \
              &Ks[bsel][w * 512 + i * 2048]);                             \
      gload16(vb + (size_t)row * Tn + (jt) * 64 + scs,                    \
              &Vs[bsel][w * 512 + i * 2048]);                             \
    }                                                                     \
  }

// P swizzle: 8-short granular, bijective within a 32-short row
#define PSW(q) ((((q) & 3) << 3) ^ (((q) & 4) << 2))

  STAGE(0, 0);
  __syncthreads();

  for (int j = 0; j < Tn / 64; ++j) {
    const int cur = j & 1;
    if (j + 1 < Tn / 64) STAGE(j + 1, cur ^ 1);

    // S = Q K^T  (C: row=q=lg*4+r+16m, col=key=lr+16n)
    short8 bk[4][2];
#pragma unroll
    for (int n = 0; n < 4; ++n)
#pragma unroll
      for (int kk = 0; kk < 2; ++kk) {
        const int row = n * 16 + lr;
        bk[n][kk] = *(const short8*)&Ks[cur][row*64 + ((kk*32 + lg*8) ^ ((row & 7) << 3))];
      }
    f32x4 s[2][4] = {};
    __builtin_amdgcn_s_setprio(1);
#pragma unroll
    for (int m = 0; m < 2; ++m)
#pragma unroll
      for (int n = 0; n < 4; ++n) {
        s[m][n] = mfma16(aq[m][0], bk[n][0], s[m][n]);
        s[m][n] = mfma16(aq[m][1], bk[n][1], s[m][n]);
      }
    __builtin_amdgcn_s_setprio(0);

    // defer-max: per-lane partial max vs stale row max
    float pm[2][4];
#pragma unroll
    for (int m = 0; m < 2; ++m)
#pragma unroll
      for (int r = 0; r < 4; ++r)
        pm[m][r] = fmaxf(fmaxf(s[m][0][r], s[m][1][r]), fmaxf(s[m][2][r], s[m][3][r]));
    int ok = 1;
#pragma unroll
    for (int m = 0; m < 2; ++m)
#pragma unroll
      for (int r = 0; r < 4; ++r)
        ok &= (pm[m][r] <= mrow[m][r] + 11.0f) ? 1 : 0;
    if (!__all(ok)) {
      float tm[2][4];
#pragma unroll
      for (int m = 0; m < 2; ++m)
#pragma unroll
        for (int r = 0; r < 4; ++r) tm[m][r] = pm[m][r];
#pragma unroll
      for (int off = 1; off < 16; off <<= 1)
#pragma unroll
        for (int m = 0; m < 2; ++m)
#pragma unroll
          for (int r = 0; r < 4; ++r)
            tm[m][r] = fmaxf(tm[m][r], __shfl_xor(tm[m][r], off));
#pragma unroll
      for (int m = 0; m < 2; ++m)
#pragma unroll
        for (int r = 0; r < 4; ++r) {
          const float mn = fmaxf(mrow[m][r], tm[m][r]);
          const float corr = __builtin_amdgcn_exp2f(mrow[m][r] - mn);
          lacc[m][r] *= corr;
#pragma unroll
          for (int dn = 0; dn < 4; ++dn) o[m][dn][r] *= corr;
          mrow[m][r] = mn;
        }
    }

    // V fragments (independent of P phases)
    short8 bv[4][2];
#pragma unroll
    for (int dn = 0; dn < 4; ++dn)
#pragma unroll
      for (int kk = 0; kk < 2; ++kk) {
        const int row = dn * 16 + lr;
        bv[dn][kk] = *(const short8*)&Vs[cur][row*64 + ((kk*32 + lg*8) ^ ((row & 7) << 3))];
      }

    // ---- phase 0: keys 0..31 (n=0,1) ----
#pragma unroll
    for (int m = 0; m < 2; ++m)
#pragma unroll
      for (int n = 0; n < 2; ++n)
#pragma unroll
        for (int r = 0; r < 4; ++r) {
          const float p = __builtin_amdgcn_exp2f(s[m][n][r] - mrow[m][r]);
          const unsigned u = __builtin_bit_cast(unsigned, p);
          const int q = m*16 + lg*4 + r;
          Pw[q*32 + ((n*16 + lr) ^ PSW(q))] = (short)(u >> 16);
        }
    short8 pa0[2];
#pragma unroll
    for (int m = 0; m < 2; ++m) {
      const int q = m*16 + lr;
      pa0[m] = *(const short8*)&Pw[q*32 + ((lg*8) ^ PSW(q))];
    }
    __builtin_amdgcn_s_setprio(1);
#pragma unroll
    for (int m = 0; m < 2; ++m) {
      lacc[m] = mfma16(pa0[m], ones, lacc[m]);
#pragma unroll
      for (int dn = 0; dn < 4; ++dn)
        o[m][dn] = mfma16(pa0[m], bv[dn][0], o[m][dn]);
    }
    __builtin_amdgcn_s_setprio(0);

    // ---- phase 1: keys 32..63 (n=2,3), same buffer (in-order DS) ----
#pragma unroll
    for (int m = 0; m < 2; ++m)
#pragma unroll
      for (int n = 0; n < 2; ++n)
#pragma unroll
        for (int r = 0; r < 4; ++r) {
          const float p = __builtin_amdgcn_exp2f(s[m][2 + n][r] - mrow[m][r]);
          const unsigned u = __builtin_bit_cast(unsigned, p);
          const int q = m*16 + lg*4 + r;
          Pw[q*32 + ((n*16 + lr) ^ PSW(q))] = (short)(u >> 16);
        }
    short8 pa1[2];
#pragma unroll
    for (int m = 0; m < 2; ++m) {
      const int q = m*16 + lr;
      pa1[m] = *(const short8*)&Pw[q*32 + ((lg*8) ^ PSW(q))];
    }
    __builtin_amdgcn_s_setprio(1);
#pragma unroll
    for (int m = 0; m < 2; ++m) {
      lacc[m] = mfma16(pa1[m], ones, lacc[m]);
#pragma unroll
      for (int dn = 0; dn < 4; ++dn)
        o[m][dn] = mfma16(pa1[m], bv[dn][1], o[m][dn]);
    }
    __builtin_amdgcn_s_setprio(0);

    __syncthreads();
  }
#undef STAGE
#undef PSW

  // normalize + store y[B][T][E] bf16 (lacc already holds full row sums)
  const int b = bh >> 4, hh = bh & 15;
  short* yb = y + (size_t)b * Tn * En + hh * 64;
#pragma unroll
  for (int m = 0; m < 2; ++m)
#pragma unroll
    for (int r = 0; r < 4; ++r) {
      const float rl = 1.0f / lacc[m][r];
      const int t = qrow0 + m*16 + lg*4 + r;
#pragma unroll
      for (int dn = 0; dn < 4; ++dn) {
        const int d = dn*16 + lr;
        yb[(size_t)t * En + d] = f2b(o[m][dn][r] * rl);
      }
    }
}

extern "C" void kernel_launch(void* const* d_in, const int* in_sizes, int n_in,
                              void* d_out, int out_size, void* d_ws, size_t ws_size,
                              hipStream_t stream) {
  const float* x     = (const float*)d_in[0];
  const float* Wqkv  = (const float*)d_in[1];
  const float* bqkv  = (const float*)d_in[2];
  const float* qg    = (const float*)d_in[3];
  const float* qb    = (const float*)d_in[4];
  const float* kg    = (const float*)d_in[5];
  const float* kb    = (const float*)d_in[6];
  const float* Wproj = (const float*)d_in[7];
  const float* bproj = (const float*)d_in[8];
  float* out = (float*)d_out;

  char* p = (char*)d_ws;
  short* xb     = (short*)p; p += (size_t)Mn * Kn * 2;
  short* wqkvT  = (short*)p; p += (size_t)N1 * Kn * 2;
  short* wprojT = (short*)p; p += (size_t)En * Kn * 2;
  short* qp     = (short*)p; p += (size_t)Mn * Kn * 2;
  short* kp     = (short*)p; p += (size_t)Mn * Kn * 2;
  short* vtb    = (short*)p; p += (size_t)Mn * Kn * 2;
  short* yb     = (short*)p; p += (size_t)Mn * Kn * 2;

  cvt_x_kernel<<<Mn * Kn / (256 * 8), 256, 0, stream>>>(x, xb);
  transpose_w_kernel<<<dim3(N1 / 32, Kn / 32), 256, 0, stream>>>(Wqkv, wqkvT, Kn, N1);
  transpose_w_kernel<<<dim3(En / 32, Kn / 32), 256, 0, stream>>>(Wproj, wprojT, Kn, En);
  // GEMM1 with fused bias + q/k LayerNorm + transposed V write
  gemm_kernel<1><<<(N1 / 128) * (Mn / 128), 256, 0, stream>>>(
      xb, wqkvT, bqkv, nullptr, qp, kp, vtb, qg, qb, kg, kb,
      N1, N1 / 128, (N1 / 128) * (Mn / 128) / 8);
  flash_kernel<<<1024, 256, 0, stream>>>(qp, kp, vtb, yb);
  gemm_kernel<0><<<(En / 128) * (Mn / 128), 256, 0, stream>>>(
      yb, wprojT, bproj, out, nullptr, nullptr, nullptr, nullptr, nullptr, nullptr, nullptr,
      En, En / 128, (En / 128) * (Mn / 128) / 8);
}